// Round 2
// baseline (261.963 us; speedup 1.0000x reference)
//
#include <hip/hip_runtime.h>

#define H 128
#define W 128
#define C 128
#define NB 4
#define HW (H * W)
#define PXB 32            // pixels per block (quarter row)
#define NSEG (W / PXB)    // 4
#define TPX 64            // pixels per transpose block

// ---------------------------------------------------------------------------
// Pre-pass 1: NCHW -> NHWC transpose of x into workspace (32 MB).
// ---------------------------------------------------------------------------
__global__ __launch_bounds__(256) void transpose_nchw_nhwc(
    const float* __restrict__ x, float* __restrict__ xt) {
  __shared__ float tile[TPX][C + 1];  // 64 x 129 floats = 33 KB
  const int blk = blockIdx.x;
  const int n = blk >> 8;                 // HW/TPX = 256 blocks per image
  const int p0 = (blk & 255) * TPX;
  const float* xn = x + (size_t)n * C * HW;
  float* xtn = xt + (size_t)n * HW * C;

  const int i = threadIdx.x & 63;         // pixel within tile
  const int c0 = threadIdx.x >> 6;        // 0..3
#pragma unroll
  for (int c = c0; c < C; c += 4)
    tile[i][c] = xn[(size_t)c * HW + p0 + i];
  __syncthreads();

  const int cl = threadIdx.x & 31;        // channel quad 0..31
  const int pr = threadIdx.x >> 5;        // 0..7
#pragma unroll
  for (int p = pr; p < TPX; p += 8) {
    float4 v = make_float4(tile[p][4 * cl + 0], tile[p][4 * cl + 1],
                           tile[p][4 * cl + 2], tile[p][4 * cl + 3]);
    *(float4*)(xtn + (size_t)(p0 + p) * C + 4 * cl) = v;
  }
}

// ---------------------------------------------------------------------------
// Pre-pass 2: weight re-layout wg[p][ch][k] -> wt[ch][k][p]  (9216 floats).
// Lets the conv load each channel's 72 weights as 18 aligned float4s.
// ---------------------------------------------------------------------------
__global__ __launch_bounds__(256) void prep_wt(
    const float* __restrict__ wg, float* __restrict__ wt) {
  const int i = blockIdx.x * 256 + threadIdx.x;  // 36 blocks x 256 = 9216
  const int ch = i / 72;
  const int rem = i % 72;
  const int k = rem >> 3;
  const int p = rem & 7;
  wt[i] = wg[((size_t)p * C + ch) * 9 + k];
}

// ---------------------------------------------------------------------------
// Fused deformable-conv kernel, all-NHWC variant.
// Block = 32 consecutive pixels of one row. 2048 blocks x 256 thr, XCD-swizzled
// so each XCD owns a contiguous 64-row band (L2 locality for row windows).
// Phase 1: 3x3 conv 128->8 from NHWC xt (float4 slabs) + float4 weights.
// Phase 2: bilinear sample from NHWC xt (float4 over channels).
// ---------------------------------------------------------------------------
__global__ __launch_bounds__(256, 4) void dcn_fused_t2(
    const float* __restrict__ xt, const float* __restrict__ wt,
    const float* __restrict__ b, float* __restrict__ out) {

  __shared__ float lacc[16][PXB][8];  // 16 KB partial conv accumulators
  __shared__ float loff[PXB][9];      // padded (stride 9) final offsets

  const int t = threadIdx.x;
  const int bxr = blockIdx.x;
  const int bx = ((bxr & 7) << 8) | (bxr >> 3);  // XCD swizzle (2048 = 8*256)
  const int seg = bx & (NSEG - 1);
  const int y = (bx >> 2) & (H - 1);
  const int n = bx >> 9;
  const int x0 = seg * PXB;

  const float* xtn = xt + (size_t)n * HW * C;

  // ---------------- Phase 1: offset conv from NHWC -------------------------
  {
    const int pp = t & 15;   // pixel pair -> pixels x0+2pp, x0+2pp+1
    const int cg = t >> 4;   // channel group 0..15 (8 channels each)
    const int xb = x0 + 2 * pp;
    const int cb = cg * 8;

    int xs[4];
    float colm[4];
#pragma unroll
    for (int j = 0; j < 4; ++j) {
      int xa = xb - 1 + j;
      colm[j] = ((unsigned)xa < (unsigned)W) ? 1.f : 0.f;
      xs[j] = xa < 0 ? 0 : (xa > W - 1 ? W - 1 : xa);
    }
    int pix[3][4];
    float m[3][4];
#pragma unroll
    for (int r = 0; r < 3; ++r) {
      int yy = y + r - 1;
      float rm = ((unsigned)yy < (unsigned)H) ? 1.f : 0.f;
      int yc = yy < 0 ? 0 : (yy > H - 1 ? H - 1 : yy);
#pragma unroll
      for (int j = 0; j < 4; ++j) {
        m[r][j] = rm * colm[j];
        pix[r][j] = yc * W + xs[j];
      }
    }

    float acc[2][8];
#pragma unroll
    for (int p = 0; p < 8; ++p) { acc[0][p] = 0.f; acc[1][p] = 0.f; }

#pragma unroll
    for (int c2 = 0; c2 < 2; ++c2) {
      // Load 12 pixels x 4 channels as float4, apply boundary mask.
      float xvq[3][4][4];
#pragma unroll
      for (int r = 0; r < 3; ++r) {
#pragma unroll
        for (int j = 0; j < 4; ++j) {
          float4 v = *(const float4*)(xtn + (size_t)pix[r][j] * C + cb + c2 * 4);
          const float mm = m[r][j];
          xvq[r][j][0] = v.x * mm;
          xvq[r][j][1] = v.y * mm;
          xvq[r][j][2] = v.z * mm;
          xvq[r][j][3] = v.w * mm;
        }
      }
#pragma unroll
      for (int cc = 0; cc < 4; ++cc) {
        const int ch = cb + c2 * 4 + cc;
        const float4* wv4 = (const float4*)(wt + (size_t)ch * 72);
#pragma unroll
        for (int k = 0; k < 9; ++k) {
          const int r = k / 3, kw = k % 3;
          const float4 wa = wv4[2 * k];      // p = 0..3
          const float4 wb = wv4[2 * k + 1];  // p = 4..7
          const float xl = xvq[r][kw][cc];
          const float xr = xvq[r][kw + 1][cc];
          acc[0][0] += xl * wa.x; acc[0][1] += xl * wa.y;
          acc[0][2] += xl * wa.z; acc[0][3] += xl * wa.w;
          acc[0][4] += xl * wb.x; acc[0][5] += xl * wb.y;
          acc[0][6] += xl * wb.z; acc[0][7] += xl * wb.w;
          acc[1][0] += xr * wa.x; acc[1][1] += xr * wa.y;
          acc[1][2] += xr * wa.z; acc[1][3] += xr * wa.w;
          acc[1][4] += xr * wb.x; acc[1][5] += xr * wb.y;
          acc[1][6] += xr * wb.z; acc[1][7] += xr * wb.w;
        }
      }
    }
#pragma unroll
    for (int p = 0; p < 8; ++p) {
      lacc[cg][2 * pp][p] = acc[0][p];
      lacc[cg][2 * pp + 1][p] = acc[1][p];
    }
  }
  __syncthreads();

  // ---------------- Phase 1.5: reduce 16 groups + bias ---------------------
  {
    const int px = t >> 3;  // 0..31
    const int p = t & 7;
    float s = b[p];
#pragma unroll
    for (int g = 0; g < 16; ++g) s += lacc[g][px][p];
    loff[px][p] = s;
  }
  __syncthreads();

  // ---------------- Phase 2: bilinear sample (NHWC float4) + store ---------
  {
    const int px = t & (PXB - 1);
    const int sg = t >> 5;  // 0..7 (16 channels each)
    const int xx = x0 + px;

    float offv[8];
#pragma unroll
    for (int q = 0; q < 8; ++q) offv[q] = loff[px][q];

    int o00[4], o01[4], o10[4], o11[4];
    float w00[4], w01[4], w10[4], w11[4];
#pragma unroll
    for (int p = 0; p < 4; ++p) {
      float sy = (float)y + offv[2 * p];
      float sx = (float)xx + offv[2 * p + 1];
      float y0f = floorf(sy), x0f = floorf(sx);
      float wy1 = sy - y0f, wx1 = sx - x0f;
      float wy0 = 1.f - wy1, wx0 = 1.f - wx1;
      int iy0 = (int)y0f, ix0 = (int)x0f;
      int iy1 = iy0 + 1, ix1 = ix0 + 1;
      float vy0 = ((unsigned)iy0 < (unsigned)H) ? 1.f : 0.f;
      float vy1 = ((unsigned)iy1 < (unsigned)H) ? 1.f : 0.f;
      float vx0 = ((unsigned)ix0 < (unsigned)W) ? 1.f : 0.f;
      float vx1 = ((unsigned)ix1 < (unsigned)W) ? 1.f : 0.f;
      int cy0 = iy0 < 0 ? 0 : (iy0 > H - 1 ? H - 1 : iy0);
      int cy1 = iy1 < 0 ? 0 : (iy1 > H - 1 ? H - 1 : iy1);
      int cx0 = ix0 < 0 ? 0 : (ix0 > W - 1 ? W - 1 : ix0);
      int cx1 = ix1 < 0 ? 0 : (ix1 > W - 1 ? W - 1 : ix1);
      o00[p] = cy0 * W + cx0; o01[p] = cy0 * W + cx1;
      o10[p] = cy1 * W + cx0; o11[p] = cy1 * W + cx1;
      w00[p] = wy0 * wx0 * vy0 * vx0;
      w01[p] = wy0 * wx1 * vy0 * vx1;
      w10[p] = wy1 * wx0 * vy1 * vx0;
      w11[p] = wy1 * wx1 * vy1 * vx1;
    }

    const float4* xt4 = (const float4*)xtn;
    float* outn = out + (size_t)n * C * (2 * H) * (2 * W);
    const int cq0 = sg * 4;  // float4 index into the 128-ch row

#pragma unroll
    for (int q = 0; q < 4; ++q) {
      const int cq = cq0 + q;
      float s[4][4];  // [p][channel-in-quad]
#pragma unroll
      for (int p = 0; p < 4; ++p) {
        float4 v00 = xt4[(size_t)o00[p] * (C / 4) + cq];
        float4 v01 = xt4[(size_t)o01[p] * (C / 4) + cq];
        float4 v10 = xt4[(size_t)o10[p] * (C / 4) + cq];
        float4 v11 = xt4[(size_t)o11[p] * (C / 4) + cq];
        s[p][0] = w00[p] * v00.x + w01[p] * v01.x + w10[p] * v10.x + w11[p] * v11.x;
        s[p][1] = w00[p] * v00.y + w01[p] * v01.y + w10[p] * v10.y + w11[p] * v11.y;
        s[p][2] = w00[p] * v00.z + w01[p] * v01.z + w10[p] * v10.z + w11[p] * v11.z;
        s[p][3] = w00[p] * v00.w + w01[p] * v01.w + w10[p] * v10.w + w11[p] * v11.w;
      }
#pragma unroll
      for (int j = 0; j < 4; ++j) {
        const int c = sg * 16 + q * 4 + j;
        float* oc = outn + (size_t)c * (2 * H) * (2 * W);
        float2* r0 = (float2*)(oc + (size_t)(2 * y) * (2 * W) + 2 * xx);
        float2* r1 = (float2*)(oc + (size_t)(2 * y + 1) * (2 * W) + 2 * xx);
        *r0 = make_float2(s[0][j], s[1][j]);
        *r1 = make_float2(s[2][j], s[3][j]);
      }
    }
  }
}

// ---------------------------------------------------------------------------
// Fallback: original NCHW-gather kernel (used only if workspace too small).
// ---------------------------------------------------------------------------
__global__ __launch_bounds__(256) void dcn_fused(
    const float* __restrict__ x, const float* __restrict__ wg,
    const float* __restrict__ b, float* __restrict__ out) {

  __shared__ float lacc[16][PXB][8];
  __shared__ float loff[PXB][9];

  const int t = threadIdx.x;
  const int bx = blockIdx.x;
  const int seg = bx & (NSEG - 1);
  const int y = (bx >> 2) & (H - 1);
  const int n = bx >> 9;
  const int x0 = seg * PXB;

  const float* xn = x + (size_t)n * C * HW;

  {
    const int pp = t & 15;
    const int cg = t >> 4;
    const int xb = x0 + 2 * pp;

    int xs[4];
    float colm[4];
#pragma unroll
    for (int j = 0; j < 4; ++j) {
      int xa = xb - 1 + j;
      colm[j] = ((unsigned)xa < (unsigned)W) ? 1.f : 0.f;
      xs[j] = xa < 0 ? 0 : (xa > W - 1 ? W - 1 : xa);
    }
    int rowo[3];
    float m[3][4];
#pragma unroll
    for (int r = 0; r < 3; ++r) {
      int yy = y + r - 1;
      float rm = ((unsigned)yy < (unsigned)H) ? 1.f : 0.f;
      int yc = yy < 0 ? 0 : (yy > H - 1 ? H - 1 : yy);
      rowo[r] = yc * W;
#pragma unroll
      for (int j = 0; j < 4; ++j) m[r][j] = rm * colm[j];
    }

    float acc[2][8];
#pragma unroll
    for (int p = 0; p < 8; ++p) { acc[0][p] = 0.f; acc[1][p] = 0.f; }

    for (int c = 0; c < 8; ++c) {
      const int ch = cg * 8 + c;
      const float* xc = xn + (size_t)ch * HW;
      float xv[3][4];
#pragma unroll
      for (int r = 0; r < 3; ++r)
#pragma unroll
        for (int j = 0; j < 4; ++j)
          xv[r][j] = xc[rowo[r] + xs[j]] * m[r][j];

      const float* wc = wg + (size_t)ch * 9;
#pragma unroll
      for (int p = 0; p < 8; ++p) {
        const float* wp = wc + (size_t)p * C * 9;
#pragma unroll
        for (int r = 0; r < 3; ++r) {
#pragma unroll
          for (int kw = 0; kw < 3; ++kw) {
            const float wv = wp[r * 3 + kw];
            acc[0][p] += xv[r][kw] * wv;
            acc[1][p] += xv[r][kw + 1] * wv;
          }
        }
      }
    }
#pragma unroll
    for (int p = 0; p < 8; ++p) {
      lacc[cg][2 * pp][p] = acc[0][p];
      lacc[cg][2 * pp + 1][p] = acc[1][p];
    }
  }
  __syncthreads();

  {
    const int px = t >> 3;
    const int p = t & 7;
    float s = b[p];
#pragma unroll
    for (int g = 0; g < 16; ++g) s += lacc[g][px][p];
    loff[px][p] = s;
  }
  __syncthreads();

  {
    const int px = t & (PXB - 1);
    const int sg = t >> 5;
    const int xx = x0 + px;

    float offv[8];
#pragma unroll
    for (int q = 0; q < 8; ++q) offv[q] = loff[px][q];

    int o00[4], o01[4], o10[4], o11[4];
    float w00[4], w01[4], w10[4], w11[4];
#pragma unroll
    for (int p = 0; p < 4; ++p) {
      float sy = (float)y + offv[2 * p];
      float sx = (float)xx + offv[2 * p + 1];
      float y0f = floorf(sy), x0f = floorf(sx);
      float wy1 = sy - y0f, wx1 = sx - x0f;
      float wy0 = 1.f - wy1, wx0 = 1.f - wx1;
      int iy0 = (int)y0f, ix0 = (int)x0f;
      int iy1 = iy0 + 1, ix1 = ix0 + 1;
      float vy0 = ((unsigned)iy0 < (unsigned)H) ? 1.f : 0.f;
      float vy1 = ((unsigned)iy1 < (unsigned)H) ? 1.f : 0.f;
      float vx0 = ((unsigned)ix0 < (unsigned)W) ? 1.f : 0.f;
      float vx1 = ((unsigned)ix1 < (unsigned)W) ? 1.f : 0.f;
      int cy0 = iy0 < 0 ? 0 : (iy0 > H - 1 ? H - 1 : iy0);
      int cy1 = iy1 < 0 ? 0 : (iy1 > H - 1 ? H - 1 : iy1);
      int cx0 = ix0 < 0 ? 0 : (ix0 > W - 1 ? W - 1 : ix0);
      int cx1 = ix1 < 0 ? 0 : (ix1 > W - 1 ? W - 1 : ix1);
      o00[p] = cy0 * W + cx0; o01[p] = cy0 * W + cx1;
      o10[p] = cy1 * W + cx0; o11[p] = cy1 * W + cx1;
      w00[p] = wy0 * wx0 * vy0 * vx0;
      w01[p] = wy0 * wx1 * vy0 * vx1;
      w10[p] = wy1 * wx0 * vy1 * vx0;
      w11[p] = wy1 * wx1 * vy1 * vx1;
    }

    float* outn = out + (size_t)n * C * (2 * H) * (2 * W);
    for (int c = sg * 16; c < sg * 16 + 16; ++c) {
      const float* xc = xn + (size_t)c * HW;
      float s[4];
#pragma unroll
      for (int p = 0; p < 4; ++p) {
        s[p] = w00[p] * xc[o00[p]] + w01[p] * xc[o01[p]] +
               w10[p] * xc[o10[p]] + w11[p] * xc[o11[p]];
      }
      float* oc = outn + (size_t)c * (2 * H) * (2 * W);
      float2* r0 = (float2*)(oc + (size_t)(2 * y) * (2 * W) + 2 * xx);
      float2* r1 = (float2*)(oc + (size_t)(2 * y + 1) * (2 * W) + 2 * xx);
      *r0 = make_float2(s[0], s[1]);
      *r1 = make_float2(s[2], s[3]);
    }
  }
}

extern "C" void kernel_launch(void* const* d_in, const int* in_sizes, int n_in,
                              void* d_out, int out_size, void* d_ws, size_t ws_size,
                              hipStream_t stream) {
  const float* x = (const float*)d_in[0];
  const float* w = (const float*)d_in[1];
  const float* b = (const float*)d_in[2];
  float* out = (float*)d_out;

  const size_t xt_bytes = (size_t)NB * HW * C * sizeof(float);  // 32 MB
  const size_t wt_bytes = (size_t)8 * C * 9 * sizeof(float);    // 36 KB
  dim3 grid(NB * H * NSEG), block(256);

  if (d_ws != nullptr && ws_size >= xt_bytes + wt_bytes) {
    float* xt = (float*)d_ws;
    float* wt = (float*)((char*)d_ws + xt_bytes);
    prep_wt<<<dim3(36), block, 0, stream>>>(w, wt);
    transpose_nchw_nhwc<<<dim3(NB * (HW / TPX)), block, 0, stream>>>(x, xt);
    dcn_fused_t2<<<grid, block, 0, stream>>>(xt, wt, b, out);
  } else {
    dcn_fused<<<grid, block, 0, stream>>>(x, w, b, out);
  }
}

// Round 3
// 231.487 us; speedup vs baseline: 1.1316x; 1.1316x over previous
//
#include <hip/hip_runtime.h>

#define H 128
#define W 128
#define C 128
#define NB 4
#define HW (H * W)
#define PXB 32            // pixels per block (quarter row)
#define NSEG (W / PXB)    // 4
#define TPX 64            // pixels per transpose block

// ---------------------------------------------------------------------------
// Pre-pass 1: NCHW -> NHWC transpose of x into workspace (32 MB).
// ---------------------------------------------------------------------------
__global__ __launch_bounds__(256) void transpose_nchw_nhwc(
    const float* __restrict__ x, float* __restrict__ xt) {
  __shared__ float tile[TPX][C + 1];  // 64 x 129 floats = 33 KB
  const int blk = blockIdx.x;
  const int n = blk >> 8;                 // HW/TPX = 256 blocks per image
  const int p0 = (blk & 255) * TPX;
  const float* xn = x + (size_t)n * C * HW;
  float* xtn = xt + (size_t)n * HW * C;

  const int i = threadIdx.x & 63;         // pixel within tile
  const int c0 = threadIdx.x >> 6;        // 0..3
#pragma unroll
  for (int c = c0; c < C; c += 4)
    tile[i][c] = xn[(size_t)c * HW + p0 + i];
  __syncthreads();

  const int cl = threadIdx.x & 31;        // channel quad 0..31
  const int pr = threadIdx.x >> 5;        // 0..7
#pragma unroll
  for (int p = pr; p < TPX; p += 8) {
    float4 v = make_float4(tile[p][4 * cl + 0], tile[p][4 * cl + 1],
                           tile[p][4 * cl + 2], tile[p][4 * cl + 3]);
    *(float4*)(xtn + (size_t)(p0 + p) * C + 4 * cl) = v;
  }
}

// ---------------------------------------------------------------------------
// Pre-pass 2: weight re-layout wg[p][ch][k] -> wt[ch][k][p]  (9216 floats).
// ---------------------------------------------------------------------------
__global__ __launch_bounds__(256) void prep_wt(
    const float* __restrict__ wg, float* __restrict__ wt) {
  const int i = blockIdx.x * 256 + threadIdx.x;  // 36 blocks x 256 = 9216
  const int ch = i / 72;
  const int rem = i % 72;
  const int k = rem >> 3;
  const int p = rem & 7;
  wt[i] = wg[((size_t)p * C + ch) * 9 + k];
}

// ---------------------------------------------------------------------------
// Fused deformable-conv, all-NHWC, channel-major gather.
// Block = 32 px of one row. 2048 blocks x 256 thr, XCD-swizzled.
// Phase 1: 3x3 conv 128->8 from NHWC xt (float4 slabs) + float4 weights.
// Phase 2: per-px tap table in LDS; gather is channel-major (lanes =
//          consecutive channel quads of the SAME tap -> ~16 lines/instr
//          instead of 64); results restaged via LDS (reusing lacc) so
//          stores stay px-major coalesced float2.
// ---------------------------------------------------------------------------
__global__ __launch_bounds__(256, 4) void dcn_fused_t3(
    const float* __restrict__ xt, const float* __restrict__ wt,
    const float* __restrict__ b, float* __restrict__ out) {

  // lacc (phase 1): [16][PXB][8] floats = 4096 floats.
  // lout (phase 2): [4][8][33] float4 = 1056 float4 = 4224 floats.  (union)
  __shared__ __align__(16) float lsh[4224];
  __shared__ float loff[PXB][9];      // final offsets (stride 9)
  __shared__ int4   ltapi[PXB][4];    // per (px,pos): o00,o01,o10,o11
  __shared__ float4 ltapw[PXB][4];    // per (px,pos): w00,w01,w10,w11

  const int t = threadIdx.x;
  const int bxr = blockIdx.x;
  const int bx = ((bxr & 7) << 8) | (bxr >> 3);  // XCD swizzle (2048 = 8*256)
  const int seg = bx & (NSEG - 1);
  const int y = (bx >> 2) & (H - 1);
  const int n = bx >> 9;
  const int x0 = seg * PXB;

  const float* xtn = xt + (size_t)n * HW * C;

  // ---------------- Phase 1: offset conv from NHWC -------------------------
  {
    const int pp = t & 15;   // pixel pair -> pixels x0+2pp, x0+2pp+1
    const int cg = t >> 4;   // channel group 0..15 (8 channels each)
    const int xb = x0 + 2 * pp;
    const int cb = cg * 8;

    int xs[4];
    float colm[4];
#pragma unroll
    for (int j = 0; j < 4; ++j) {
      int xa = xb - 1 + j;
      colm[j] = ((unsigned)xa < (unsigned)W) ? 1.f : 0.f;
      xs[j] = xa < 0 ? 0 : (xa > W - 1 ? W - 1 : xa);
    }
    int pix[3][4];
    float m[3][4];
#pragma unroll
    for (int r = 0; r < 3; ++r) {
      int yy = y + r - 1;
      float rm = ((unsigned)yy < (unsigned)H) ? 1.f : 0.f;
      int yc = yy < 0 ? 0 : (yy > H - 1 ? H - 1 : yy);
#pragma unroll
      for (int j = 0; j < 4; ++j) {
        m[r][j] = rm * colm[j];
        pix[r][j] = yc * W + xs[j];
      }
    }

    float acc[2][8];
#pragma unroll
    for (int p = 0; p < 8; ++p) { acc[0][p] = 0.f; acc[1][p] = 0.f; }

#pragma unroll
    for (int c2 = 0; c2 < 2; ++c2) {
      float xvq[3][4][4];
#pragma unroll
      for (int r = 0; r < 3; ++r) {
#pragma unroll
        for (int j = 0; j < 4; ++j) {
          float4 v = *(const float4*)(xtn + (size_t)pix[r][j] * C + cb + c2 * 4);
          const float mm = m[r][j];
          xvq[r][j][0] = v.x * mm;
          xvq[r][j][1] = v.y * mm;
          xvq[r][j][2] = v.z * mm;
          xvq[r][j][3] = v.w * mm;
        }
      }
#pragma unroll
      for (int cc = 0; cc < 4; ++cc) {
        const int ch = cb + c2 * 4 + cc;
        const float4* wv4 = (const float4*)(wt + (size_t)ch * 72);
#pragma unroll
        for (int k = 0; k < 9; ++k) {
          const int r = k / 3, kw = k % 3;
          const float4 wa = wv4[2 * k];      // p = 0..3
          const float4 wb = wv4[2 * k + 1];  // p = 4..7
          const float xl = xvq[r][kw][cc];
          const float xr = xvq[r][kw + 1][cc];
          acc[0][0] += xl * wa.x; acc[0][1] += xl * wa.y;
          acc[0][2] += xl * wa.z; acc[0][3] += xl * wa.w;
          acc[0][4] += xl * wb.x; acc[0][5] += xl * wb.y;
          acc[0][6] += xl * wb.z; acc[0][7] += xl * wb.w;
          acc[1][0] += xr * wa.x; acc[1][1] += xr * wa.y;
          acc[1][2] += xr * wa.z; acc[1][3] += xr * wa.w;
          acc[1][4] += xr * wb.x; acc[1][5] += xr * wb.y;
          acc[1][6] += xr * wb.z; acc[1][7] += xr * wb.w;
        }
      }
    }
#pragma unroll
    for (int p = 0; p < 8; ++p) {
      lsh[((size_t)cg * PXB + 2 * pp) * 8 + p] = acc[0][p];
      lsh[((size_t)cg * PXB + 2 * pp + 1) * 8 + p] = acc[1][p];
    }
  }
  __syncthreads();

  // ---------------- Phase 1.5: reduce 16 groups + bias ---------------------
  {
    const int px = t >> 3;  // 0..31
    const int p = t & 7;
    float s = b[p];
#pragma unroll
    for (int g = 0; g < 16; ++g) s += lsh[((size_t)g * PXB + px) * 8 + p];
    loff[px][p] = s;
  }
  __syncthreads();

  // ---------------- Phase 1.75: per (px,pos) tap table ---------------------
  if (t < 128) {
    const int px = t >> 2;
    const int pos = t & 3;
    const int xx = x0 + px;
    float sy = (float)y + loff[px][2 * pos];
    float sx = (float)xx + loff[px][2 * pos + 1];
    float y0f = floorf(sy), x0f = floorf(sx);
    float wy1 = sy - y0f, wx1 = sx - x0f;
    float wy0 = 1.f - wy1, wx0 = 1.f - wx1;
    int iy0 = (int)y0f, ix0 = (int)x0f;
    int iy1 = iy0 + 1, ix1 = ix0 + 1;
    float vy0 = ((unsigned)iy0 < (unsigned)H) ? 1.f : 0.f;
    float vy1 = ((unsigned)iy1 < (unsigned)H) ? 1.f : 0.f;
    float vx0 = ((unsigned)ix0 < (unsigned)W) ? 1.f : 0.f;
    float vx1 = ((unsigned)ix1 < (unsigned)W) ? 1.f : 0.f;
    int cy0 = iy0 < 0 ? 0 : (iy0 > H - 1 ? H - 1 : iy0);
    int cy1 = iy1 < 0 ? 0 : (iy1 > H - 1 ? H - 1 : iy1);
    int cx0 = ix0 < 0 ? 0 : (ix0 > W - 1 ? W - 1 : ix0);
    int cx1 = ix1 < 0 ? 0 : (ix1 > W - 1 ? W - 1 : ix1);
    ltapi[px][pos] = make_int4(cy0 * W + cx0, cy0 * W + cx1,
                               cy1 * W + cx0, cy1 * W + cx1);
    ltapw[px][pos] = make_float4(wy0 * wx0 * vy0 * vx0, wy0 * wx1 * vy0 * vx1,
                                 wy1 * wx0 * vy1 * vx0, wy1 * wx1 * vy1 * vx1);
  }
  __syncthreads();

  // ---------------- Phase 2: channel-major gather + LDS restage ------------
  {
    const int cq = t & 31;   // channel quad 0..31 (full 128 channels)
    const int pg = t >> 5;   // pixel-in-pass 0..7
    const int spx = t & 7;   // store px-in-pass
    const int cg4 = t >> 3;  // store channel quad 0..31
    const float4* xt4 = (const float4*)xtn;
    float4* lout4 = (float4*)lsh;   // [4][8][33] float4, idx (pos*8+pg)*33+cq
    float* outn = out + (size_t)n * C * (2 * H) * (2 * W);

    for (int pass = 0; pass < 4; ++pass) {
      const int px = pass * 8 + pg;
      float4 sacc[4];
#pragma unroll
      for (int pos = 0; pos < 4; ++pos) {
        const int4 o = ltapi[px][pos];
        const float4 wv = ltapw[px][pos];
        float4 v00 = xt4[(size_t)o.x * (C / 4) + cq];
        float4 v01 = xt4[(size_t)o.y * (C / 4) + cq];
        float4 v10 = xt4[(size_t)o.z * (C / 4) + cq];
        float4 v11 = xt4[(size_t)o.w * (C / 4) + cq];
        sacc[pos].x = wv.x * v00.x + wv.y * v01.x + wv.z * v10.x + wv.w * v11.x;
        sacc[pos].y = wv.x * v00.y + wv.y * v01.y + wv.z * v10.y + wv.w * v11.y;
        sacc[pos].z = wv.x * v00.z + wv.y * v01.z + wv.z * v10.z + wv.w * v11.z;
        sacc[pos].w = wv.x * v00.w + wv.y * v01.w + wv.z * v10.w + wv.w * v11.w;
      }
      __syncthreads();  // WAR: previous pass's lout reads done
#pragma unroll
      for (int pos = 0; pos < 4; ++pos)
        lout4[(pos * 8 + pg) * 33 + cq] = sacc[pos];
      __syncthreads();

      // store: px-major coalesced float2
      float4 v[4];
#pragma unroll
      for (int pos = 0; pos < 4; ++pos)
        v[pos] = lout4[(pos * 8 + spx) * 33 + cg4];
      const int xg = x0 + pass * 8 + spx;
      float* obase = outn + (size_t)(2 * y) * (2 * W) + 2 * xg;
#define STORE_CH(J, CMP)                                                      \
      {                                                                       \
        float* oc = obase + (size_t)(cg4 * 4 + J) * (4 * HW);                 \
        *(float2*)oc = make_float2(v[0].CMP, v[1].CMP);                       \
        *(float2*)(oc + 2 * W) = make_float2(v[2].CMP, v[3].CMP);             \
      }
      STORE_CH(0, x) STORE_CH(1, y) STORE_CH(2, z) STORE_CH(3, w)
#undef STORE_CH
    }
  }
}

// ---------------------------------------------------------------------------
// Fallback: original NCHW-gather kernel (used only if workspace too small).
// ---------------------------------------------------------------------------
__global__ __launch_bounds__(256) void dcn_fused(
    const float* __restrict__ x, const float* __restrict__ wg,
    const float* __restrict__ b, float* __restrict__ out) {

  __shared__ float lacc[16][PXB][8];
  __shared__ float loff[PXB][9];

  const int t = threadIdx.x;
  const int bx = blockIdx.x;
  const int seg = bx & (NSEG - 1);
  const int y = (bx >> 2) & (H - 1);
  const int n = bx >> 9;
  const int x0 = seg * PXB;

  const float* xn = x + (size_t)n * C * HW;

  {
    const int pp = t & 15;
    const int cg = t >> 4;
    const int xb = x0 + 2 * pp;

    int xs[4];
    float colm[4];
#pragma unroll
    for (int j = 0; j < 4; ++j) {
      int xa = xb - 1 + j;
      colm[j] = ((unsigned)xa < (unsigned)W) ? 1.f : 0.f;
      xs[j] = xa < 0 ? 0 : (xa > W - 1 ? W - 1 : xa);
    }
    int rowo[3];
    float m[3][4];
#pragma unroll
    for (int r = 0; r < 3; ++r) {
      int yy = y + r - 1;
      float rm = ((unsigned)yy < (unsigned)H) ? 1.f : 0.f;
      int yc = yy < 0 ? 0 : (yy > H - 1 ? H - 1 : yy);
      rowo[r] = yc * W;
#pragma unroll
      for (int j = 0; j < 4; ++j) m[r][j] = rm * colm[j];
    }

    float acc[2][8];
#pragma unroll
    for (int p = 0; p < 8; ++p) { acc[0][p] = 0.f; acc[1][p] = 0.f; }

    for (int c = 0; c < 8; ++c) {
      const int ch = cg * 8 + c;
      const float* xc = xn + (size_t)ch * HW;
      float xv[3][4];
#pragma unroll
      for (int r = 0; r < 3; ++r)
#pragma unroll
        for (int j = 0; j < 4; ++j)
          xv[r][j] = xc[rowo[r] + xs[j]] * m[r][j];

      const float* wc = wg + (size_t)ch * 9;
#pragma unroll
      for (int p = 0; p < 8; ++p) {
        const float* wp = wc + (size_t)p * C * 9;
#pragma unroll
        for (int r = 0; r < 3; ++r) {
#pragma unroll
          for (int kw = 0; kw < 3; ++kw) {
            const float wv = wp[r * 3 + kw];
            acc[0][p] += xv[r][kw] * wv;
            acc[1][p] += xv[r][kw + 1] * wv;
          }
        }
      }
    }
#pragma unroll
    for (int p = 0; p < 8; ++p) {
      lacc[cg][2 * pp][p] = acc[0][p];
      lacc[cg][2 * pp + 1][p] = acc[1][p];
    }
  }
  __syncthreads();

  {
    const int px = t >> 3;
    const int p = t & 7;
    float s = b[p];
#pragma unroll
    for (int g = 0; g < 16; ++g) s += lacc[g][px][p];
    loff[px][p] = s;
  }
  __syncthreads();

  {
    const int px = t & (PXB - 1);
    const int sg = t >> 5;
    const int xx = x0 + px;

    float offv[8];
#pragma unroll
    for (int q = 0; q < 8; ++q) offv[q] = loff[px][q];

    int o00[4], o01[4], o10[4], o11[4];
    float w00[4], w01[4], w10[4], w11[4];
#pragma unroll
    for (int p = 0; p < 4; ++p) {
      float sy = (float)y + offv[2 * p];
      float sx = (float)xx + offv[2 * p + 1];
      float y0f = floorf(sy), x0f = floorf(sx);
      float wy1 = sy - y0f, wx1 = sx - x0f;
      float wy0 = 1.f - wy1, wx0 = 1.f - wx1;
      int iy0 = (int)y0f, ix0 = (int)x0f;
      int iy1 = iy0 + 1, ix1 = ix0 + 1;
      float vy0 = ((unsigned)iy0 < (unsigned)H) ? 1.f : 0.f;
      float vy1 = ((unsigned)iy1 < (unsigned)H) ? 1.f : 0.f;
      float vx0 = ((unsigned)ix0 < (unsigned)W) ? 1.f : 0.f;
      float vx1 = ((unsigned)ix1 < (unsigned)W) ? 1.f : 0.f;
      int cy0 = iy0 < 0 ? 0 : (iy0 > H - 1 ? H - 1 : iy0);
      int cy1 = iy1 < 0 ? 0 : (iy1 > H - 1 ? H - 1 : iy1);
      int cx0 = ix0 < 0 ? 0 : (ix0 > W - 1 ? W - 1 : ix0);
      int cx1 = ix1 < 0 ? 0 : (ix1 > W - 1 ? W - 1 : ix1);
      o00[p] = cy0 * W + cx0; o01[p] = cy0 * W + cx1;
      o10[p] = cy1 * W + cx0; o11[p] = cy1 * W + cx1;
      w00[p] = wy0 * wx0 * vy0 * vx0;
      w01[p] = wy0 * wx1 * vy0 * vx1;
      w10[p] = wy1 * wx0 * vy1 * vx0;
      w11[p] = wy1 * wx1 * vy1 * vx1;
    }

    float* outn = out + (size_t)n * C * (2 * H) * (2 * W);
    for (int c = sg * 16; c < sg * 16 + 16; ++c) {
      const float* xc = xn + (size_t)c * HW;
      float s[4];
#pragma unroll
      for (int p = 0; p < 4; ++p) {
        s[p] = w00[p] * xc[o00[p]] + w01[p] * xc[o01[p]] +
               w10[p] * xc[o10[p]] + w11[p] * xc[o11[p]];
      }
      float* oc = outn + (size_t)c * (2 * H) * (2 * W);
      float2* r0 = (float2*)(oc + (size_t)(2 * y) * (2 * W) + 2 * xx);
      float2* r1 = (float2*)(oc + (size_t)(2 * y + 1) * (2 * W) + 2 * xx);
      *r0 = make_float2(s[0], s[1]);
      *r1 = make_float2(s[2], s[3]);
    }
  }
}

extern "C" void kernel_launch(void* const* d_in, const int* in_sizes, int n_in,
                              void* d_out, int out_size, void* d_ws, size_t ws_size,
                              hipStream_t stream) {
  const float* x = (const float*)d_in[0];
  const float* w = (const float*)d_in[1];
  const float* b = (const float*)d_in[2];
  float* out = (float*)d_out;

  const size_t xt_bytes = (size_t)NB * HW * C * sizeof(float);  // 32 MB
  const size_t wt_bytes = (size_t)8 * C * 9 * sizeof(float);    // 36 KB
  dim3 grid(NB * H * NSEG), block(256);

  if (d_ws != nullptr && ws_size >= xt_bytes + wt_bytes) {
    float* xt = (float*)d_ws;
    float* wt = (float*)((char*)d_ws + xt_bytes);
    prep_wt<<<dim3(36), block, 0, stream>>>(w, wt);
    transpose_nchw_nhwc<<<dim3(NB * (HW / TPX)), block, 0, stream>>>(x, xt);
    dcn_fused_t3<<<grid, block, 0, stream>>>(xt, wt, b, out);
  } else {
    dcn_fused<<<grid, block, 0, stream>>>(x, w, b, out);
  }
}